// Round 1
// baseline (3405.482 us; speedup 1.0000x reference)
//
#include <hip/hip_runtime.h>

// CUBA LIF constants
#define THRV 1.25f
#define CDF 0.75f   // 1 - CURRENT_DECAY
#define VDF 0.97f   // 1 - VOLTAGE_DECAY

constexpr int B = 64, I = 700, H = 2048, O = 20, T = 100;
constexpr int TP = 112;   // padded T for x tile (7 * 16)
constexpr int LDZ = 101;  // pitch for z/s scan tiles (odd -> conflict-free columns)

// Fused GEMM + CUBA scan.
// Per block: computes z[h,t] = sum_c W[h0+h, c] * X[b, c, t] for 64 h, all 100 t,
// then runs the sequential LIF scan in LDS and writes spikes + pre-reset voltages.
__global__ __launch_bounds__(256) void gemm_scan(
    const float* __restrict__ W,   // [H, K]
    const float* __restrict__ X,   // [B, K, T]
    int K, long xbs,               // X batch stride in elements
    float* __restrict__ S,         // [B, H, T] spikes out (this layer)
    float* __restrict__ V)         // [B, H, T] voltages out (this layer)
{
    __shared__ float xs[16][TP];
    __shared__ float wl[64][16];
    __shared__ float zt[64][LDZ];
    __shared__ float st[64][LDZ];

    const int tid = threadIdx.x;
    const int tx = tid & 15;       // t-lane
    const int ty = tid >> 4;       // h-lane
    const int b  = blockIdx.y;
    const int h0 = blockIdx.x * 64;
    const float* Xb = X + (long)b * xbs;

    float acc[4][7];
    #pragma unroll
    for (int k = 0; k < 4; ++k)
        #pragma unroll
        for (int j = 0; j < 7; ++j) acc[k][j] = 0.f;

    for (int cc = 0; cc < K; cc += 16) {
        // stage X tile [16 c][100 t] (zero-padded to TP)
        for (int idx = tid; idx < 16 * TP; idx += 256) {
            int c = idx / TP, t = idx - c * TP;
            float v = 0.f;
            if (t < T && cc + c < K) v = Xb[(long)(cc + c) * T + t];
            xs[c][t] = v;
        }
        // stage W tile [64 h][16 c]
        for (int idx = tid; idx < 64 * 16; idx += 256) {
            int h = idx >> 4, c = idx & 15;
            float v = 0.f;
            if (cc + c < K) v = W[(long)(h0 + h) * K + cc + c];
            wl[h][c] = v;
        }
        __syncthreads();
        #pragma unroll
        for (int c = 0; c < 16; ++c) {
            float wv[4], xv[7];
            #pragma unroll
            for (int k = 0; k < 4; ++k) wv[k] = wl[ty + 16 * k][c];
            #pragma unroll
            for (int j = 0; j < 7; ++j) xv[j] = xs[c][tx + 16 * j];
            #pragma unroll
            for (int k = 0; k < 4; ++k)
                #pragma unroll
                for (int j = 0; j < 7; ++j)
                    acc[k][j] = fmaf(wv[k], xv[j], acc[k][j]);
        }
        __syncthreads();
    }

    // park z in LDS for the scan
    #pragma unroll
    for (int k = 0; k < 4; ++k)
        #pragma unroll
        for (int j = 0; j < 7; ++j) {
            int t = tx + 16 * j;
            if (t < T) zt[ty + 16 * k][t] = acc[k][j];
        }
    __syncthreads();

    // sequential LIF scan: 64 independent chains, one per h row (wave 0 only)
    if (tid < 64) {
        float cur = 0.f, v = 0.f;
        for (int t = 0; t < T; ++t) {
            cur = fmaf(CDF, cur, zt[tid][t]);
            v   = fmaf(VDF, v, cur);
            float s = (v >= THRV) ? 1.f : 0.f;
            st[tid][t] = s;
            zt[tid][t] = v;            // pre-reset voltage
            v *= (1.f - s);            // hard reset
        }
    }
    __syncthreads();

    // coalesced write-out: block's region is one contiguous 6400-float run
    long base = (long)b * H * T + (long)h0 * T;
    for (int idx = tid; idx < 64 * T; idx += 256) {
        int h = idx / T, t = idx - h * T;
        S[base + idx] = st[h][t];
        V[base + idx] = zt[h][t];
    }
}

// Readouts: r[l,b,o,t] = sum_h ro_l[o,h] * s_l[b,h,t]
__global__ __launch_bounds__(128) void readout_kernel(
    const float* __restrict__ ro0, const float* __restrict__ ro1,
    const float* __restrict__ Sall,   // [2,B,H,T] spikes (already written)
    float* __restrict__ R)            // [2,B,O,T]
{
    int bid = blockIdx.x;             // l*B*O + b*O + o
    int l = bid / (B * O);
    int rem = bid - l * (B * O);
    int b = rem / O, o = rem - (rem / O) * O;
    int t = threadIdx.x;
    if (t >= T) return;

    const float* ro = (l == 0 ? ro0 : ro1) + (long)o * H;
    const float* s  = Sall + (long)l * B * H * T + (long)b * H * T + t;
    float acc = 0.f;
    #pragma unroll 8
    for (int h = 0; h < H; ++h)
        acc = fmaf(ro[h], s[(long)h * T], acc);
    R[(long)l * B * O * T + (long)b * O * T + (long)o * T + t] = acc;
}

extern "C" void kernel_launch(void* const* d_in, const int* in_sizes, int n_in,
                              void* d_out, int out_size, void* d_ws, size_t ws_size,
                              hipStream_t stream) {
    const float* spike = (const float*)d_in[0];  // [B, I, T]
    const float* w0    = (const float*)d_in[1];  // [H, I]
    const float* w1    = (const float*)d_in[2];  // [H, H]
    const float* ro0   = (const float*)d_in[3];  // [O, H]
    const float* ro1   = (const float*)d_in[4];  // [O, H]

    float* out = (float*)d_out;
    float* S = out;                                   // [2,B,H,T]
    float* R = out + 2L * B * H * T;                  // [2,B,O,T]
    float* V = out + 2L * B * H * T + 2L * B * O * T; // [2,B,H,T]

    dim3 grid(H / 64, B);
    // layer 0: z0 = w0 @ spike -> scan -> s0, v0
    gemm_scan<<<grid, 256, 0, stream>>>(w0, spike, I, (long)I * T, S, V);
    // layer 1: z1 = w1 @ s0 -> scan -> s1, v1  (reads s0 from d_out)
    gemm_scan<<<grid, 256, 0, stream>>>(w1, S, H, (long)H * T,
                                        S + (long)B * H * T, V + (long)B * H * T);
    // readouts
    readout_kernel<<<2 * B * O, 128, 0, stream>>>(ro0, ro1, S, R);
}

// Round 2
// 488.618 us; speedup vs baseline: 6.9696x; 6.9696x over previous
//
#include <hip/hip_runtime.h>

using f16x8 = __attribute__((ext_vector_type(8))) _Float16;
using f32x4 = __attribute__((ext_vector_type(4))) float;

constexpr int B = 64, I = 700, H = 2048, O = 20, T = 100;
constexpr int TP = 112;    // padded T
constexpr int KP0 = 704;   // padded I (11 * 64)

// ---------------- pre-pass: split-f16 weight conversion ----------------
// W fp32 [Hn][K] -> hi/lo f16 [Hn][Kp], zero-padded in K.
__global__ __launch_bounds__(256) void convert_w_split(
    const float* __restrict__ w, int K, int Kp, int n,
    unsigned short* __restrict__ hi, unsigned short* __restrict__ lo)
{
    int idx = blockIdx.x * 256 + threadIdx.x;
    if (idx >= n) return;
    int h = idx / Kp, c = idx - h * Kp;
    float f = (c < K) ? w[(size_t)h * K + c] : 0.f;
    _Float16 fh = (_Float16)f;
    float r = f - (float)fh;
    _Float16 fl = (_Float16)r;
    hi[idx] = *(unsigned short*)&fh;
    lo[idx] = *(unsigned short*)&fl;
}

// ---------------- pre-pass: transpose spike input to [B, TP, KP0] f16 ----
__global__ __launch_bounds__(256) void transpose_x(
    const float* __restrict__ X, unsigned short* __restrict__ XT)
{
    __shared__ float xs[64][101];
    int b = blockIdx.y, c0 = blockIdx.x * 64;
    const float* Xb = X + (size_t)b * I * T;
    for (int idx = threadIdx.x; idx < 64 * T; idx += 256) {
        int c = idx / T, t = idx - (idx / T) * T;
        xs[c][t] = (c0 + c < I) ? Xb[(size_t)(c0 + c) * T + t] : 0.f;
    }
    __syncthreads();
    unsigned short* Ob = XT + (size_t)b * TP * KP0 + c0;
    for (int idx = threadIdx.x; idx < TP * 64; idx += 256) {
        int t = idx >> 6, c = idx & 63;
        float v = (t < T) ? xs[c][t] : 0.f;
        _Float16 hv = (_Float16)v;
        Ob[(size_t)t * KP0 + c] = *(unsigned short*)&hv;
    }
}

// ---------------- fused MFMA GEMM + CUBA scan ----------------
// z[h,t] = sum_c (Whi+Wlo)[h,c] * XT[b,t,c]; then LIF scan over t in LDS.
// Block: 64 h x 112 t for one b; 4 waves, each 16 h x 112 t.
__global__ __launch_bounds__(256) void gemm_scan_mfma(
    const unsigned short* __restrict__ Whi, const unsigned short* __restrict__ Wlo,
    const unsigned short* __restrict__ XT, int Kp,
    float* __restrict__ S, float* __restrict__ V, unsigned short* __restrict__ sT)
{
    // union: GEMM phase {whi[64][64], wlo[64][64], xs[112][64]} = 30 KB
    //        scan phase {zt[64][101], st[64][101]} f32 = 51.7 KB
    __shared__ __align__(16) char smem[51712];
    unsigned short* whi = (unsigned short*)smem;
    unsigned short* wlo = whi + 4096;
    unsigned short* xs  = wlo + 4096;
    float* zt = (float*)smem;
    float* st = zt + 6464;

    const int tid = threadIdx.x;
    const int lane = tid & 63, wave = tid >> 6;
    const int b = blockIdx.y, h0 = blockIdx.x * 64;
    const unsigned short* XTb = XT + (size_t)b * TP * Kp;

    f32x4 acc[7];
    #pragma unroll
    for (int nt = 0; nt < 7; ++nt) acc[nt] = (f32x4){0.f, 0.f, 0.f, 0.f};

    const int lm = lane & 15, lg = lane >> 4;
    const int rowA = wave * 16 + lm;
    int offA[2], obB[2];
    #pragma unroll
    for (int kh = 0; kh < 2; ++kh) {
        offA[kh] = rowA * 64 + (((kh * 4 + lg) ^ (rowA & 7)) << 3);
        obB[kh]  = lm * 64   + (((kh * 4 + lg) ^ (lm & 7)) << 3);
    }

    for (int cc = 0; cc < Kp; cc += 64) {
        // stage W hi/lo [64][64] and X [112][64], XOR-swizzled 16B chunks
        #pragma unroll
        for (int i = 0; i < 2; ++i) {
            int q = tid + i * 256;            // 0..511
            int row = q >> 3, g = q & 7;
            int d = row * 64 + ((g ^ (row & 7)) << 3);
            size_t src = (size_t)(h0 + row) * Kp + cc + g * 8;
            *(f16x8*)&whi[d] = *(const f16x8*)&Whi[src];
            *(f16x8*)&wlo[d] = *(const f16x8*)&Wlo[src];
        }
        for (int q = tid; q < 896; q += 256) { // 112 rows x 8 chunks
            int t = q >> 3, g = q & 7;
            int d = t * 64 + ((g ^ (t & 7)) << 3);
            *(f16x8*)&xs[d] = *(const f16x8*)&XTb[(size_t)t * Kp + cc + g * 8];
        }
        __syncthreads();
        #pragma unroll
        for (int kh = 0; kh < 2; ++kh) {
            f16x8 ah = *(const f16x8*)&whi[offA[kh]];
            f16x8 al = *(const f16x8*)&wlo[offA[kh]];
            #pragma unroll
            for (int nt = 0; nt < 7; ++nt) {
                f16x8 bx = *(const f16x8*)&xs[obB[kh] + nt * 1024];
                acc[nt] = __builtin_amdgcn_mfma_f32_16x16x32_f16(ah, bx, acc[nt], 0, 0, 0);
                acc[nt] = __builtin_amdgcn_mfma_f32_16x16x32_f16(al, bx, acc[nt], 0, 0, 0);
            }
        }
        __syncthreads();
    }

    // acc -> zt LDS. D layout: col(t) = lane&15, row(h) = (lane>>4)*4 + reg.
    #pragma unroll
    for (int nt = 0; nt < 7; ++nt) {
        int t = nt * 16 + lm;
        if (t < T) {
            #pragma unroll
            for (int r = 0; r < 4; ++r) {
                int h = wave * 16 + lg * 4 + r;
                zt[h * 101 + t] = acc[nt][r];
            }
        }
    }
    __syncthreads();

    // sequential LIF scan, one chain per h (wave 0)
    if (tid < 64) {
        float cur = 0.f, v = 0.f;
        for (int t = 0; t < T; ++t) {
            cur = fmaf(0.75f, cur, zt[tid * 101 + t]);
            v   = fmaf(0.97f, v, cur);
            float s = (v >= 1.25f) ? 1.f : 0.f;
            st[tid * 101 + t] = s;
            zt[tid * 101 + t] = v;   // pre-reset voltage
            v *= (1.f - s);
        }
    }
    __syncthreads();

    size_t base = (size_t)b * H * T + (size_t)h0 * T;
    for (int idx = tid; idx < 64 * T; idx += 256) {
        int h = idx / T, t = idx - (idx / T) * T;
        S[base + idx] = st[h * 101 + t];
        V[base + idx] = zt[h * 101 + t];
    }
    if (sT) {  // transposed f16 spikes for next layer's B operand (zero-pad t>=T)
        unsigned short* Ob = sT + (size_t)b * TP * H + h0;
        for (int idx = tid; idx < TP * 64; idx += 256) {
            int t = idx >> 6, h = idx & 63;
            float v = (t < T) ? st[h * 101 + t] : 0.f;
            _Float16 hv = (_Float16)v;
            Ob[(size_t)t * H + h] = *(unsigned short*)&hv;
        }
    }
}

// ---------------- readouts (fp32, reads S from d_out) ----------------
__global__ __launch_bounds__(128) void readout_kernel(
    const float* __restrict__ ro0, const float* __restrict__ ro1,
    const float* __restrict__ Sall, float* __restrict__ R)
{
    int bid = blockIdx.x;
    int l = bid / (B * O);
    int rem = bid - l * (B * O);
    int b = rem / O, o = rem - (rem / O) * O;
    int t = threadIdx.x;
    if (t >= T) return;
    const float* ro = (l == 0 ? ro0 : ro1) + (size_t)o * H;
    const float* s  = Sall + (size_t)l * B * H * T + (size_t)b * H * T + t;
    float acc = 0.f;
    #pragma unroll 8
    for (int h = 0; h < H; ++h)
        acc = fmaf(ro[h], s[(size_t)h * T], acc);
    R[(size_t)l * B * O * T + (size_t)b * O * T + (size_t)o * T + t] = acc;
}

// ---------------- fallback fp32 path (round-1, known correct) ----------------
__global__ __launch_bounds__(256) void gemm_scan_f32(
    const float* __restrict__ W, const float* __restrict__ X,
    int K, long xbs, float* __restrict__ S, float* __restrict__ V)
{
    __shared__ float fxs[16][112];
    __shared__ float fwl[64][16];
    __shared__ float fzt[64][101];
    __shared__ float fst[64][101];
    const int tid = threadIdx.x;
    const int tx = tid & 15, ty = tid >> 4;
    const int b = blockIdx.y, h0 = blockIdx.x * 64;
    const float* Xb = X + (long)b * xbs;
    float acc[4][7];
    #pragma unroll
    for (int k = 0; k < 4; ++k)
        #pragma unroll
        for (int j = 0; j < 7; ++j) acc[k][j] = 0.f;
    for (int cc = 0; cc < K; cc += 16) {
        for (int idx = tid; idx < 16 * 112; idx += 256) {
            int c = idx / 112, t = idx - c * 112;
            float v = 0.f;
            if (t < T && cc + c < K) v = Xb[(long)(cc + c) * T + t];
            fxs[c][t] = v;
        }
        for (int idx = tid; idx < 64 * 16; idx += 256) {
            int h = idx >> 4, c = idx & 15;
            float v = 0.f;
            if (cc + c < K) v = W[(long)(h0 + h) * K + cc + c];
            fwl[h][c] = v;
        }
        __syncthreads();
        #pragma unroll
        for (int c = 0; c < 16; ++c) {
            float wv[4], xv[7];
            #pragma unroll
            for (int k = 0; k < 4; ++k) wv[k] = fwl[ty + 16 * k][c];
            #pragma unroll
            for (int j = 0; j < 7; ++j) xv[j] = fxs[c][tx + 16 * j];
            #pragma unroll
            for (int k = 0; k < 4; ++k)
                #pragma unroll
                for (int j = 0; j < 7; ++j)
                    acc[k][j] = fmaf(wv[k], xv[j], acc[k][j]);
        }
        __syncthreads();
    }
    #pragma unroll
    for (int k = 0; k < 4; ++k)
        #pragma unroll
        for (int j = 0; j < 7; ++j) {
            int t = tx + 16 * j;
            if (t < T) fzt[ty + 16 * k][t] = acc[k][j];
        }
    __syncthreads();
    if (tid < 64) {
        float cur = 0.f, v = 0.f;
        for (int t = 0; t < T; ++t) {
            cur = fmaf(0.75f, cur, fzt[tid][t]);
            v = fmaf(0.97f, v, cur);
            float s = (v >= 1.25f) ? 1.f : 0.f;
            fst[tid][t] = s;
            fzt[tid][t] = v;
            v *= (1.f - s);
        }
    }
    __syncthreads();
    long base = (long)b * H * T + (long)h0 * T;
    for (int idx = tid; idx < 64 * T; idx += 256) {
        int h = idx / T, t = idx - (idx / T) * T;
        S[base + idx] = fst[h][t];
        V[base + idx] = fzt[h][t];
    }
}

extern "C" void kernel_launch(void* const* d_in, const int* in_sizes, int n_in,
                              void* d_out, int out_size, void* d_ws, size_t ws_size,
                              hipStream_t stream) {
    const float* spike = (const float*)d_in[0];
    const float* w0    = (const float*)d_in[1];
    const float* w1    = (const float*)d_in[2];
    const float* ro0   = (const float*)d_in[3];
    const float* ro1   = (const float*)d_in[4];

    float* out = (float*)d_out;
    float* S = out;
    float* R = out + 2L * B * H * T;
    float* V = out + 2L * B * H * T + 2L * B * O * T;

    // ws layout (ushorts)
    const size_t nW0 = (size_t)H * KP0;       // 1,441,792
    const size_t nW1 = (size_t)H * H;         // 4,194,304
    const size_t nXT = (size_t)B * TP * KP0;  // 5,046,272
    const size_t nST = (size_t)B * TP * H;    // 14,680,064
    const size_t need = (2 * nW0 + 2 * nW1 + nXT + nST) * sizeof(unsigned short);

    if (ws_size >= need) {
        unsigned short* p = (unsigned short*)d_ws;
        unsigned short* w0h = p; p += nW0;
        unsigned short* w0l = p; p += nW0;
        unsigned short* w1h = p; p += nW1;
        unsigned short* w1l = p; p += nW1;
        unsigned short* xt0 = p; p += nXT;
        unsigned short* s0t = p; p += nST;

        int n0 = (int)nW0, n1 = (int)nW1;
        convert_w_split<<<(n0 + 255) / 256, 256, 0, stream>>>(w0, I, KP0, n0, w0h, w0l);
        convert_w_split<<<(n1 + 255) / 256, 256, 0, stream>>>(w1, H, H, n1, w1h, w1l);
        transpose_x<<<dim3(KP0 / 64, B), 256, 0, stream>>>(spike, xt0);

        dim3 grid(H / 64, B);
        gemm_scan_mfma<<<grid, 256, 0, stream>>>(w0h, w0l, xt0, KP0, S, V, s0t);
        gemm_scan_mfma<<<grid, 256, 0, stream>>>(w1h, w1l, s0t, H,
                                                 S + (size_t)B * H * T,
                                                 V + (size_t)B * H * T, nullptr);
    } else {
        dim3 grid(H / 64, B);
        gemm_scan_f32<<<grid, 256, 0, stream>>>(w0, spike, I, (long)I * T, S, V);
        gemm_scan_f32<<<grid, 256, 0, stream>>>(w1, S, H, (long)H * T,
                                                S + (long)B * H * T, V + (long)B * H * T);
    }
    readout_kernel<<<2 * B * O, 128, 0, stream>>>(ro0, ro1, S, R);
}

// Round 3
// 360.268 us; speedup vs baseline: 9.4526x; 1.3563x over previous
//
#include <hip/hip_runtime.h>

using f16x8 = __attribute__((ext_vector_type(8))) _Float16;
using f32x4 = __attribute__((ext_vector_type(4))) float;
using u16x8 = __attribute__((ext_vector_type(8))) unsigned short;

constexpr int B = 64, I = 700, H = 2048, O = 20, T = 100;
constexpr int NKT0 = 11;        // K-tiles layer 0 (704 = 11*64)
constexpr int NKT1 = 32;        // K-tiles layer 1 (2048 = 32*64)
constexpr int A_ELEM = 8192;    // ushorts per A image: 128 rows (64 hi + 64 lo) x 64
constexpr int B_ELEM = 7168;    // ushorts per B image: 112 rows (t) x 64
constexpr int BUF_BYTES = 30720;
constexpr int A_CHUNKS = 1024, TOT_CHUNKS = 1920;

#define GLOAD16(gp, lp) __builtin_amdgcn_global_load_lds( \
    (const __attribute__((address_space(1))) unsigned int*)(const void*)(gp), \
    (__attribute__((address_space(3))) unsigned int*)(void*)(lp), 16, 0, 0)

// ---------------- pre-pass: W fp32 -> split-f16 A-images, pre-swizzled ----------
// dst layout: [h0blk(32)][kt(NKT)][chunk(1024) * 8 f16]; chunk c = (row r, slot s);
// data octet g = s ^ (r&7); rows 0-63 = hi, 64-127 = lo.
__global__ __launch_bounds__(256) void convert_w_tiled(
    const float* __restrict__ w, int K, int NKT, int total,
    unsigned short* __restrict__ dst)
{
    int idx = blockIdx.x * 256 + threadIdx.x;
    if (idx >= total) return;
    int img = idx >> 10, c = idx & 1023;
    int h0blk = img / NKT, kt = img - h0blk * NKT;
    int r = c >> 3, s8 = c & 7;
    int sp = r >> 6, hr = r & 63;
    int kbase = kt * 64 + ((s8 ^ (r & 7)) << 3);
    const float* wrow = w + (size_t)(h0blk * 64 + hr) * K;
    u16x8 outv;
    #pragma unroll
    for (int j = 0; j < 8; ++j) {
        int k = kbase + j;
        float f = (k < K) ? wrow[k] : 0.f;
        _Float16 hi = (_Float16)f;
        _Float16 val = (sp == 0) ? hi : (_Float16)(f - (float)hi);
        outv[j] = *(unsigned short*)&val;
    }
    *(u16x8*)&dst[(size_t)idx * 8] = outv;
}

// ---------------- pre-pass: X fp32 [B][I][T] -> pre-swizzled B-images ----------
// dst: [b][kt(NKT0)][chunk(896) * 8 f16]; chunk = (row r=t, slot s); octet g = s^(r&7).
__global__ __launch_bounds__(256) void transpose_x_tiled(
    const float* __restrict__ X, unsigned short* __restrict__ XT)
{
    __shared__ float xs[64][101];
    int kt = blockIdx.x, b = blockIdx.y;
    int c0 = kt * 64;
    const float* Xb = X + (size_t)b * I * T;
    for (int idx = threadIdx.x; idx < 64 * T; idx += 256) {
        int ci = idx / T, t = idx - (idx / T) * T;
        xs[ci][t] = (c0 + ci < I) ? Xb[(size_t)(c0 + ci) * T + t] : 0.f;
    }
    __syncthreads();
    unsigned short* dst = XT + ((size_t)b * NKT0 + kt) * B_ELEM;
    for (int idx = threadIdx.x; idx < 896; idx += 256) {
        int r = idx >> 3, s8 = idx & 7;
        int ci0 = (s8 ^ (r & 7)) << 3;
        u16x8 outv;
        #pragma unroll
        for (int j = 0; j < 8; ++j) {
            float f = (r < T) ? xs[ci0 + j][r] : 0.f;
            _Float16 h = (_Float16)f;
            outv[j] = *(unsigned short*)&h;
        }
        *(u16x8*)&dst[(size_t)idx * 8] = outv;
    }
}

// ---------------- fused MFMA GEMM (2-phase gload_lds pipeline) + CUBA scan ------
// Block: 64 h x 112 t, one b. 4 waves as 2(h) x 2(t); wc=1 waves own 48 t.
__global__ __launch_bounds__(256, 2) void gemm_scan_mfma2(
    const unsigned short* __restrict__ WA,   // [32][NKT][A_ELEM]
    const unsigned short* __restrict__ XB,   // [64][NKT][B_ELEM]
    int NKT,
    float* __restrict__ S, float* __restrict__ V,
    unsigned short* __restrict__ sT)         // [64][NKT1][B_ELEM] or null
{
    __shared__ __align__(16) char smem[2 * BUF_BYTES];
    const int tid = threadIdx.x;
    const int lane = tid & 63, wave = tid >> 6;
    const int lm = lane & 15, lg = lane >> 4;
    const int wr = wave >> 1, wc = wave & 1;
    const int NTW = 4 - wc;

    // XCD-aware decode: blocks with same b land on same XCD (X slab L2-resident)
    int orig = blockIdx.x;
    int xcd = orig & 7, slot = orig >> 3;
    int b = xcd * 8 + (slot & 7);
    int h0blk = slot >> 3;

    const unsigned short* WAblk = WA + (size_t)h0blk * NKT * A_ELEM;
    const unsigned short* XBb   = XB + (size_t)b * NKT * B_ELEM;

    // LDS fragment byte offsets (within one buffer), swizzled
    int offA[2][2][2], offB[4][2];
    #pragma unroll
    for (int sp = 0; sp < 2; ++sp)
        #pragma unroll
        for (int ar = 0; ar < 2; ++ar)
            #pragma unroll
            for (int kh = 0; kh < 2; ++kh) {
                int row = sp * 64 + wr * 32 + ar * 16 + lm;
                int g = kh * 4 + lg;
                offA[sp][ar][kh] = row * 128 + ((g ^ (row & 7)) << 4);
            }
    #pragma unroll
    for (int nt = 0; nt < 4; ++nt)
        #pragma unroll
        for (int kh = 0; kh < 2; ++kh) {
            int row = wc * 64 + nt * 16 + lm;
            int g = kh * 4 + lg;
            offB[nt][kh] = 16384 + row * 128 + ((g ^ (row & 7)) << 4);
        }

    f32x4 acc[2][4];
    #pragma unroll
    for (int ar = 0; ar < 2; ++ar)
        #pragma unroll
        for (int nt = 0; nt < 4; ++nt)
            acc[ar][nt] = (f32x4){0.f, 0.f, 0.f, 0.f};

    // prologue: stage kt=0 into buf 0
    #pragma unroll
    for (int j = 0; j < 8; ++j) {
        int idx = tid + j * 256;
        if (idx < TOT_CHUNKS) {
            char* lb = smem + ((idx & ~63) << 4);
            const unsigned short* g = (idx < A_CHUNKS) ? WAblk + (size_t)idx * 8
                                                       : XBb + (size_t)(idx - A_CHUNKS) * 8;
            GLOAD16(g, lb);
        }
    }
    __syncthreads();

    for (int kt = 0; kt < NKT; ++kt) {
        int cur = kt & 1;
        if (kt + 1 < NKT) {   // stage next tile into other buffer (DMA, no ds_write)
            const unsigned short* wa = WAblk + (size_t)(kt + 1) * A_ELEM;
            const unsigned short* xb = XBb + (size_t)(kt + 1) * B_ELEM;
            int nb = (cur ^ 1) * BUF_BYTES;
            #pragma unroll
            for (int j = 0; j < 8; ++j) {
                int idx = tid + j * 256;
                if (idx < TOT_CHUNKS) {
                    char* lb = smem + nb + ((idx & ~63) << 4);
                    const unsigned short* g = (idx < A_CHUNKS) ? wa + (size_t)idx * 8
                                                               : xb + (size_t)(idx - A_CHUNKS) * 8;
                    GLOAD16(g, lb);
                }
            }
        }
        const char* base = smem + cur * BUF_BYTES;
        f16x8 afr[2][2][2], bfr[4][2];
        #pragma unroll
        for (int sp = 0; sp < 2; ++sp)
            #pragma unroll
            for (int ar = 0; ar < 2; ++ar)
                #pragma unroll
                for (int kh = 0; kh < 2; ++kh)
                    afr[sp][ar][kh] = *(const f16x8*)(base + offA[sp][ar][kh]);
        #pragma unroll
        for (int nt = 0; nt < 4; ++nt) {
            if (nt >= NTW) continue;
            #pragma unroll
            for (int kh = 0; kh < 2; ++kh)
                bfr[nt][kh] = *(const f16x8*)(base + offB[nt][kh]);
        }
        #pragma unroll
        for (int kh = 0; kh < 2; ++kh)
            #pragma unroll
            for (int ar = 0; ar < 2; ++ar)
                #pragma unroll
                for (int nt = 0; nt < 4; ++nt) {
                    if (nt >= NTW) continue;
                    acc[ar][nt] = __builtin_amdgcn_mfma_f32_16x16x32_f16(
                        afr[0][ar][kh], bfr[nt][kh], acc[ar][nt], 0, 0, 0);
                    acc[ar][nt] = __builtin_amdgcn_mfma_f32_16x16x32_f16(
                        afr[1][ar][kh], bfr[nt][kh], acc[ar][nt], 0, 0, 0);
                }
        __syncthreads();   // drains vmcnt -> next buffer ready; cur fully read
    }

    // ---- scan phase: reuse LDS ----
    float* zt = (float*)smem;                                   // [64][113] f32
    unsigned short* st = (unsigned short*)(smem + 28928);       // [64][113] f16
    #pragma unroll
    for (int ar = 0; ar < 2; ++ar)
        #pragma unroll
        for (int nt = 0; nt < 4; ++nt) {
            if (nt >= NTW) continue;
            int t = wc * 64 + nt * 16 + lm;
            #pragma unroll
            for (int r = 0; r < 4; ++r) {
                int h = wr * 32 + ar * 16 + lg * 4 + r;
                zt[h * 113 + t] = acc[ar][nt][r];
            }
        }
    __syncthreads();

    if (tid < 64) {
        float cur = 0.f, v = 0.f;
        for (int t = 0; t < T; ++t) {
            cur = fmaf(0.75f, cur, zt[tid * 113 + t]);
            v   = fmaf(0.97f, v, cur);
            float s = (v >= 1.25f) ? 1.f : 0.f;
            st[tid * 113 + t] = (s != 0.f) ? 0x3C00 : 0;  // f16 1.0 / 0.0
            zt[tid * 113 + t] = v;                         // pre-reset voltage
            v *= (1.f - s);
        }
        for (int t = T; t < 113; ++t) st[tid * 113 + t] = 0;
    }
    __syncthreads();

    size_t gbase = ((size_t)b * H + h0blk * 64) * T;
    for (int idx = tid; idx < 1600; idx += 256) {
        int h = idx / 25, q = idx - (idx / 25) * 25;
        int t0 = q * 4;
        f32x4 sv, vv;
        #pragma unroll
        for (int i = 0; i < 4; ++i) {
            sv[i] = st[h * 113 + t0 + i] ? 1.f : 0.f;
            vv[i] = zt[h * 113 + t0 + i];
        }
        *(f32x4*)&S[gbase + (size_t)h * 100 + t0] = sv;
        *(f32x4*)&V[gbase + (size_t)h * 100 + t0] = vv;
    }
    if (sT) {  // emit pre-swizzled B-image tile for next layer (kt = h0blk)
        unsigned short* dst = sT + ((size_t)b * NKT1 + h0blk) * B_ELEM;
        for (int idx = tid; idx < 896; idx += 256) {
            int r = idx >> 3, s8 = idx & 7;
            int c0 = (s8 ^ (r & 7)) << 3;
            u16x8 outv;
            #pragma unroll
            for (int j = 0; j < 8; ++j)
                outv[j] = st[(c0 + j) * 113 + r];
            *(u16x8*)&dst[(size_t)idx * 8] = outv;
        }
    }
}

// ---------------- readouts (fp32, reads S from d_out) ----------------
__global__ __launch_bounds__(128) void readout_kernel(
    const float* __restrict__ ro0, const float* __restrict__ ro1,
    const float* __restrict__ Sall, float* __restrict__ R)
{
    int bid = blockIdx.x;
    int l = bid / (B * O);
    int rem = bid - l * (B * O);
    int b = rem / O, o = rem - (rem / O) * O;
    int t = threadIdx.x;
    if (t >= T) return;
    const float* ro = (l == 0 ? ro0 : ro1) + (size_t)o * H;
    const float* s  = Sall + (size_t)l * B * H * T + (size_t)b * H * T + t;
    float acc = 0.f;
    #pragma unroll 8
    for (int h = 0; h < H; ++h)
        acc = fmaf(ro[h], s[(size_t)h * T], acc);
    R[(size_t)l * B * O * T + (size_t)b * O * T + (size_t)o * T + t] = acc;
}

// ---------------- fallback fp32 path (round-1, known correct) ----------------
__global__ __launch_bounds__(256) void gemm_scan_f32(
    const float* __restrict__ W, const float* __restrict__ X,
    int K, long xbs, float* __restrict__ S, float* __restrict__ V)
{
    __shared__ float fxs[16][112];
    __shared__ float fwl[64][16];
    __shared__ float fzt[64][101];
    __shared__ float fst[64][101];
    const int tid = threadIdx.x;
    const int tx = tid & 15, ty = tid >> 4;
    const int b = blockIdx.y, h0 = blockIdx.x * 64;
    const float* Xb = X + (long)b * xbs;
    float acc[4][7];
    #pragma unroll
    for (int k = 0; k < 4; ++k)
        #pragma unroll
        for (int j = 0; j < 7; ++j) acc[k][j] = 0.f;
    for (int cc = 0; cc < K; cc += 16) {
        for (int idx = tid; idx < 16 * 112; idx += 256) {
            int c = idx / 112, t = idx - c * 112;
            float v = 0.f;
            if (t < T && cc + c < K) v = Xb[(long)(cc + c) * T + t];
            fxs[c][t] = v;
        }
        for (int idx = tid; idx < 64 * 16; idx += 256) {
            int h = idx >> 4, c = idx & 15;
            float v = 0.f;
            if (cc + c < K) v = W[(long)(h0 + h) * K + cc + c];
            fwl[h][c] = v;
        }
        __syncthreads();
        #pragma unroll
        for (int c = 0; c < 16; ++c) {
            float wv[4], xv[7];
            #pragma unroll
            for (int k = 0; k < 4; ++k) wv[k] = fwl[ty + 16 * k][c];
            #pragma unroll
            for (int j = 0; j < 7; ++j) xv[j] = fxs[c][tx + 16 * j];
            #pragma unroll
            for (int k = 0; k < 4; ++k)
                #pragma unroll
                for (int j = 0; j < 7; ++j)
                    acc[k][j] = fmaf(wv[k], xv[j], acc[k][j]);
        }
        __syncthreads();
    }
    #pragma unroll
    for (int k = 0; k < 4; ++k)
        #pragma unroll
        for (int j = 0; j < 7; ++j) {
            int t = tx + 16 * j;
            if (t < T) fzt[ty + 16 * k][t] = acc[k][j];
        }
    __syncthreads();
    if (tid < 64) {
        float cur = 0.f, v = 0.f;
        for (int t = 0; t < T; ++t) {
            cur = fmaf(0.75f, cur, fzt[tid][t]);
            v = fmaf(0.97f, v, cur);
            float s = (v >= 1.25f) ? 1.f : 0.f;
            fst[tid][t] = s;
            fzt[tid][t] = v;
            v *= (1.f - s);
        }
    }
    __syncthreads();
    long base = (long)b * H * T + (long)h0 * T;
    for (int idx = tid; idx < 64 * T; idx += 256) {
        int h = idx / T, t = idx - (idx / T) * T;
        S[base + idx] = fst[h][t];
        V[base + idx] = fzt[h][t];
    }
}

extern "C" void kernel_launch(void* const* d_in, const int* in_sizes, int n_in,
                              void* d_out, int out_size, void* d_ws, size_t ws_size,
                              hipStream_t stream) {
    const float* spike = (const float*)d_in[0];
    const float* w0    = (const float*)d_in[1];
    const float* w1    = (const float*)d_in[2];
    const float* ro0   = (const float*)d_in[3];
    const float* ro1   = (const float*)d_in[4];

    float* out = (float*)d_out;
    float* S = out;
    float* R = out + 2L * B * H * T;
    float* V = out + 2L * B * H * T + 2L * B * O * T;

    const size_t nW0 = (size_t)32 * NKT0 * A_ELEM;   // 2,883,584
    const size_t nW1 = (size_t)32 * NKT1 * A_ELEM;   // 8,388,608
    const size_t nX0 = (size_t)B * NKT0 * B_ELEM;    // 5,046,272
    const size_t nS0 = (size_t)B * NKT1 * B_ELEM;    // 14,680,064
    const size_t need = (nW0 + nW1 + nX0 + nS0) * sizeof(unsigned short);

    if (ws_size >= need) {
        unsigned short* p = (unsigned short*)d_ws;
        unsigned short* w0img = p; p += nW0;
        unsigned short* w1img = p; p += nW1;
        unsigned short* x0img = p; p += nX0;
        unsigned short* s0img = p; p += nS0;

        int t0 = 32 * NKT0 * 1024, t1 = 32 * NKT1 * 1024;
        convert_w_tiled<<<(t0 + 255) / 256, 256, 0, stream>>>(w0, I, NKT0, t0, w0img);
        convert_w_tiled<<<(t1 + 255) / 256, 256, 0, stream>>>(w1, H, NKT1, t1, w1img);
        transpose_x_tiled<<<dim3(NKT0, B), 256, 0, stream>>>(spike, x0img);

        gemm_scan_mfma2<<<2048, 256, 0, stream>>>(w0img, x0img, NKT0, S, V, s0img);
        gemm_scan_mfma2<<<2048, 256, 0, stream>>>(w1img, s0img, NKT1,
                                                  S + (size_t)B * H * T,
                                                  V + (size_t)B * H * T, nullptr);
    } else {
        dim3 grid(H / 64, B);
        gemm_scan_f32<<<grid, 256, 0, stream>>>(w0, spike, I, (long)I * T, S, V);
        gemm_scan_f32<<<grid, 256, 0, stream>>>(w1, S, H, (long)H * T,
                                                S + (long)B * H * T, V + (long)B * H * T);
    }
    readout_kernel<<<2 * B * O, 128, 0, stream>>>(ro0, ro1, S, R);
}

// Round 5
// 328.331 us; speedup vs baseline: 10.3721x; 1.0973x over previous
//
#include <hip/hip_runtime.h>

using f16x8 = __attribute__((ext_vector_type(8))) _Float16;
using f32x4 = __attribute__((ext_vector_type(4))) float;
using u16x8 = __attribute__((ext_vector_type(8))) unsigned short;

constexpr int B = 64, I = 700, H = 2048, O = 20, T = 100;
constexpr int NKT0 = 11;        // K-tiles layer 0 (704 = 11*64)
constexpr int NKT1 = 32;        // K-tiles layer 1 (2048 = 32*64)
constexpr int A_ELEM = 8192;    // ushorts per A image: 128 rows (64 hi + 64 lo) x 64
constexpr int B_ELEM = 7168;    // ushorts per B image: 112 rows (t) x 64
constexpr int BUF_BYTES = 30720;
constexpr int A_CHUNKS = 1024, TOT_CHUNKS = 1920;

#define GLOAD16(gp, lp) __builtin_amdgcn_global_load_lds( \
    (const __attribute__((address_space(1))) unsigned int*)(const void*)(gp), \
    (__attribute__((address_space(3))) unsigned int*)(void*)(lp), 16, 0, 0)

// ---------------- pre-pass: W fp32 -> split-f16 A-images, pre-swizzled ----------
__global__ __launch_bounds__(256) void convert_w_tiled(
    const float* __restrict__ w, int K, int NKT, int total,
    unsigned short* __restrict__ dst)
{
    int idx = blockIdx.x * 256 + threadIdx.x;
    if (idx >= total) return;
    int img = idx >> 10, c = idx & 1023;
    int h0blk = img / NKT, kt = img - h0blk * NKT;
    int r = c >> 3, s8 = c & 7;
    int sp = r >> 6, hr = r & 63;
    int kbase = kt * 64 + ((s8 ^ (r & 7)) << 3);
    const float* wrow = w + (size_t)(h0blk * 64 + hr) * K;
    u16x8 outv;
    #pragma unroll
    for (int j = 0; j < 8; ++j) {
        int k = kbase + j;
        float f = (k < K) ? wrow[k] : 0.f;
        _Float16 hi = (_Float16)f;
        _Float16 val = (sp == 0) ? hi : (_Float16)(f - (float)hi);
        outv[j] = *(unsigned short*)&val;
    }
    *(u16x8*)&dst[(size_t)idx * 8] = outv;
}

// ---------------- pre-pass: X fp32 [B][I][T] -> pre-swizzled B-images ----------
__global__ __launch_bounds__(256) void transpose_x_tiled(
    const float* __restrict__ X, unsigned short* __restrict__ XT)
{
    __shared__ float xs[64][101];
    int kt = blockIdx.x, b = blockIdx.y;
    int c0 = kt * 64;
    const float* Xb = X + (size_t)b * I * T;
    for (int idx = threadIdx.x; idx < 64 * T; idx += 256) {
        int ci = idx / T, t = idx - (idx / T) * T;
        xs[ci][t] = (c0 + ci < I) ? Xb[(size_t)(c0 + ci) * T + t] : 0.f;
    }
    __syncthreads();
    unsigned short* dst = XT + ((size_t)b * NKT0 + kt) * B_ELEM;
    for (int idx = threadIdx.x; idx < 896; idx += 256) {
        int r = idx >> 3, s8 = idx & 7;
        int ci0 = (s8 ^ (r & 7)) << 3;
        u16x8 outv;
        #pragma unroll
        for (int j = 0; j < 8; ++j) {
            float f = (r < T) ? xs[ci0 + j][r] : 0.f;
            _Float16 h = (_Float16)f;
            outv[j] = *(unsigned short*)&h;
        }
        *(u16x8*)&dst[(size_t)idx * 8] = outv;
    }
}

// ------ fused MFMA GEMM (2-phase gload_lds pipeline) + CUBA scan + readout ------
__global__ __launch_bounds__(256, 2) void gemm_scan_mfma2(
    const unsigned short* __restrict__ WA,   // [32][NKT][A_ELEM]
    const unsigned short* __restrict__ XB,   // [64][NKT][B_ELEM]
    int NKT,
    const float* __restrict__ ro,            // [O][H] this layer's readout weights
    float* __restrict__ Rl,                  // [B][O][T] this layer's readout (atomic)
    float* __restrict__ S, float* __restrict__ V,
    unsigned short* __restrict__ sT)         // [64][NKT1][B_ELEM] or null
{
    __shared__ __align__(16) char smem[2 * BUF_BYTES];
    const int tid = threadIdx.x;
    const int lane = tid & 63, wave = tid >> 6;
    const int lm = lane & 15, lg = lane >> 4;
    const int wr = wave >> 1, wc = wave & 1;
    const int NTW = 4 - wc;

    // XCD-aware decode: blocks with same b land on same XCD
    int orig = blockIdx.x;
    int xcd = orig & 7, slot = orig >> 3;
    int b = xcd * 8 + (slot & 7);
    int h0blk = slot >> 3;

    const unsigned short* WAblk = WA + (size_t)h0blk * NKT * A_ELEM;
    const unsigned short* XBb   = XB + (size_t)b * NKT * B_ELEM;

    int offA[2][2][2], offB[4][2];
    #pragma unroll
    for (int sp = 0; sp < 2; ++sp)
        #pragma unroll
        for (int ar = 0; ar < 2; ++ar)
            #pragma unroll
            for (int kh = 0; kh < 2; ++kh) {
                int row = sp * 64 + wr * 32 + ar * 16 + lm;
                int g = kh * 4 + lg;
                offA[sp][ar][kh] = row * 128 + ((g ^ (row & 7)) << 4);
            }
    #pragma unroll
    for (int nt = 0; nt < 4; ++nt)
        #pragma unroll
        for (int kh = 0; kh < 2; ++kh) {
            int row = wc * 64 + nt * 16 + lm;
            int g = kh * 4 + lg;
            offB[nt][kh] = 16384 + row * 128 + ((g ^ (row & 7)) << 4);
        }

    f32x4 acc[2][4];
    #pragma unroll
    for (int ar = 0; ar < 2; ++ar)
        #pragma unroll
        for (int nt = 0; nt < 4; ++nt)
            acc[ar][nt] = (f32x4){0.f, 0.f, 0.f, 0.f};

    // prologue: stage kt=0 into buf 0
    #pragma unroll
    for (int j = 0; j < 8; ++j) {
        int idx = tid + j * 256;
        if (idx < TOT_CHUNKS) {
            char* lb = smem + ((idx & ~63) << 4);
            const unsigned short* g = (idx < A_CHUNKS) ? WAblk + (size_t)idx * 8
                                                       : XBb + (size_t)(idx - A_CHUNKS) * 8;
            GLOAD16(g, lb);
        }
    }
    __syncthreads();

    for (int kt = 0; kt < NKT; ++kt) {
        int cur = kt & 1;
        if (kt + 1 < NKT) {
            const unsigned short* wa = WAblk + (size_t)(kt + 1) * A_ELEM;
            const unsigned short* xb = XBb + (size_t)(kt + 1) * B_ELEM;
            int nb = (cur ^ 1) * BUF_BYTES;
            #pragma unroll
            for (int j = 0; j < 8; ++j) {
                int idx = tid + j * 256;
                if (idx < TOT_CHUNKS) {
                    char* lb = smem + nb + ((idx & ~63) << 4);
                    const unsigned short* g = (idx < A_CHUNKS) ? wa + (size_t)idx * 8
                                                               : xb + (size_t)(idx - A_CHUNKS) * 8;
                    GLOAD16(g, lb);
                }
            }
        }
        const char* base = smem + cur * BUF_BYTES;
        f16x8 afr[2][2][2], bfr[4][2];
        #pragma unroll
        for (int sp = 0; sp < 2; ++sp)
            #pragma unroll
            for (int ar = 0; ar < 2; ++ar)
                #pragma unroll
                for (int kh = 0; kh < 2; ++kh)
                    afr[sp][ar][kh] = *(const f16x8*)(base + offA[sp][ar][kh]);
        #pragma unroll
        for (int nt = 0; nt < 4; ++nt) {
            if (nt >= NTW) continue;
            #pragma unroll
            for (int kh = 0; kh < 2; ++kh)
                bfr[nt][kh] = *(const f16x8*)(base + offB[nt][kh]);
        }
        #pragma unroll
        for (int kh = 0; kh < 2; ++kh)
            #pragma unroll
            for (int ar = 0; ar < 2; ++ar)
                #pragma unroll
                for (int nt = 0; nt < 4; ++nt) {
                    if (nt >= NTW) continue;
                    acc[ar][nt] = __builtin_amdgcn_mfma_f32_16x16x32_f16(
                        afr[0][ar][kh], bfr[nt][kh], acc[ar][nt], 0, 0, 0);
                    acc[ar][nt] = __builtin_amdgcn_mfma_f32_16x16x32_f16(
                        afr[1][ar][kh], bfr[nt][kh], acc[ar][nt], 0, 0, 0);
                }
        __syncthreads();
    }

    // ---- scan phase: reuse LDS ----
    float* zt  = (float*)smem;                      // [64] stride 109 f32 (27904 B)
    float* st  = (float*)(smem + 27904);            // [64] stride 108 f32 (27648 B)
    float* rol = (float*)(smem + 55552);            // [20] stride 65 f32 (5200 B)

    #pragma unroll
    for (int ar = 0; ar < 2; ++ar)
        #pragma unroll
        for (int nt = 0; nt < 4; ++nt) {
            if (nt >= NTW) continue;
            int t = wc * 64 + nt * 16 + lm;
            if (t < T) {   // padded t-columns (100..111) would overflow stride-109 rows
                #pragma unroll
                for (int r = 0; r < 4; ++r) {
                    int h = wr * 32 + ar * 16 + lg * 4 + r;
                    zt[h * 109 + t] = acc[ar][nt][r];
                }
            }
        }
    __syncthreads();

    if (tid < 64) {
        // sequential LIF scan, one chain per h
        float cur = 0.f, v = 0.f;
        for (int t = 0; t < T; ++t) {
            cur = fmaf(0.75f, cur, zt[tid * 109 + t]);
            v   = fmaf(0.97f, v, cur);
            float s = (v >= 1.25f) ? 1.f : 0.f;
            st[tid * 108 + t] = s;
            zt[tid * 109 + t] = v;   // pre-reset voltage
            v *= (1.f - s);
        }
        #pragma unroll
        for (int t = T; t < 108; ++t) st[tid * 108 + t] = 0.f;
    } else {
        // concurrently stage readout weight tile ro[0:20][h0:h0+64]
        for (int idx = tid - 64; idx < 1280; idx += 192) {
            int o = idx >> 6, h = idx & 63;
            rol[o * 65 + h] = ro[(size_t)o * H + h0blk * 64 + h];
        }
    }
    __syncthreads();

    // ---- fused partial readout: atomicAdd into Rl ----
    #pragma unroll
    for (int pass = 0; pass < 2; ++pass) {
        int idx = tid + pass * 256;
        if (idx < 500) {
            int o = idx / 25, tq = idx - o * 25, t0 = tq * 4;
            f32x4 a = (f32x4){0.f, 0.f, 0.f, 0.f};
            #pragma unroll 8
            for (int h = 0; h < 64; ++h) {
                float w = rol[o * 65 + h];
                f32x4 sv = *(const f32x4*)&st[h * 108 + t0];
                a[0] = fmaf(w, sv[0], a[0]);
                a[1] = fmaf(w, sv[1], a[1]);
                a[2] = fmaf(w, sv[2], a[2]);
                a[3] = fmaf(w, sv[3], a[3]);
            }
            float* rp = &Rl[((size_t)b * O + o) * T + t0];
            atomicAdd(rp + 0, a[0]);
            atomicAdd(rp + 1, a[1]);
            atomicAdd(rp + 2, a[2]);
            atomicAdd(rp + 3, a[3]);
        }
    }

    // ---- global write-out S, V ----
    size_t gbase = ((size_t)b * H + h0blk * 64) * T;
    for (int idx = tid; idx < 1600; idx += 256) {
        int h = idx / 25, q = idx - (idx / 25) * 25;
        int t0 = q * 4;
        f32x4 sv = *(const f32x4*)&st[h * 108 + t0];
        f32x4 vv;
        #pragma unroll
        for (int i = 0; i < 4; ++i) vv[i] = zt[h * 109 + t0 + i];
        *(f32x4*)&S[gbase + (size_t)h * 100 + t0] = sv;
        *(f32x4*)&V[gbase + (size_t)h * 100 + t0] = vv;
    }
    if (sT) {  // pre-swizzled B-image tile for next layer (kt = h0blk)
        unsigned short* dst = sT + ((size_t)b * NKT1 + h0blk) * B_ELEM;
        for (int idx = tid; idx < 896; idx += 256) {
            int r = idx >> 3, s8 = idx & 7;
            int c0 = (s8 ^ (r & 7)) << 3;
            u16x8 outv;
            #pragma unroll
            for (int j = 0; j < 8; ++j) {
                float f = (r < T) ? st[(c0 + j) * 108 + r] : 0.f;
                _Float16 hv = (_Float16)f;
                outv[j] = *(unsigned short*)&hv;
            }
            *(u16x8*)&dst[(size_t)idx * 8] = outv;
        }
    }
}

// ---------------- standalone readout (fallback path only) ----------------
__global__ __launch_bounds__(128) void readout_kernel(
    const float* __restrict__ ro0, const float* __restrict__ ro1,
    const float* __restrict__ Sall, float* __restrict__ R)
{
    int bid = blockIdx.x;
    int l = bid / (B * O);
    int rem = bid - l * (B * O);
    int b = rem / O, o = rem - (rem / O) * O;
    int t = threadIdx.x;
    if (t >= T) return;
    const float* ro = (l == 0 ? ro0 : ro1) + (size_t)o * H;
    const float* s  = Sall + (size_t)l * B * H * T + (size_t)b * H * T + t;
    float acc = 0.f;
    #pragma unroll 8
    for (int h = 0; h < H; ++h)
        acc = fmaf(ro[h], s[(size_t)h * T], acc);
    R[(size_t)l * B * O * T + (size_t)b * O * T + (size_t)o * T + t] = acc;
}

// ---------------- fallback fp32 path (round-1, known correct) ----------------
__global__ __launch_bounds__(256) void gemm_scan_f32(
    const float* __restrict__ W, const float* __restrict__ X,
    int K, long xbs, float* __restrict__ S, float* __restrict__ V)
{
    __shared__ float fxs[16][112];
    __shared__ float fwl[64][16];
    __shared__ float fzt[64][101];
    __shared__ float fst[64][101];
    const int tid = threadIdx.x;
    const int tx = tid & 15, ty = tid >> 4;
    const int b = blockIdx.y, h0 = blockIdx.x * 64;
    const float* Xb = X + (long)b * xbs;
    float acc[4][7];
    #pragma unroll
    for (int k = 0; k < 4; ++k)
        #pragma unroll
        for (int j = 0; j < 7; ++j) acc[k][j] = 0.f;
    for (int cc = 0; cc < K; cc += 16) {
        for (int idx = tid; idx < 16 * 112; idx += 256) {
            int c = idx / 112, t = idx - c * 112;
            float v = 0.f;
            if (t < T && cc + c < K) v = Xb[(long)(cc + c) * T + t];
            fxs[c][t] = v;
        }
        for (int idx = tid; idx < 64 * 16; idx += 256) {
            int h = idx >> 4, c = idx & 15;
            float v = 0.f;
            if (cc + c < K) v = W[(long)(h0 + h) * K + cc + c];
            fwl[h][c] = v;
        }
        __syncthreads();
        #pragma unroll
        for (int c = 0; c < 16; ++c) {
            float wv[4], xv[7];
            #pragma unroll
            for (int k = 0; k < 4; ++k) wv[k] = fwl[ty + 16 * k][c];
            #pragma unroll
            for (int j = 0; j < 7; ++j) xv[j] = fxs[c][tx + 16 * j];
            #pragma unroll
            for (int k = 0; k < 4; ++k)
                #pragma unroll
                for (int j = 0; j < 7; ++j)
                    acc[k][j] = fmaf(wv[k], xv[j], acc[k][j]);
        }
        __syncthreads();
    }
    #pragma unroll
    for (int k = 0; k < 4; ++k)
        #pragma unroll
        for (int j = 0; j < 7; ++j) {
            int t = tx + 16 * j;
            if (t < T) fzt[ty + 16 * k][t] = acc[k][j];
        }
    __syncthreads();
    if (tid < 64) {
        float cur = 0.f, v = 0.f;
        for (int t = 0; t < T; ++t) {
            cur = fmaf(0.75f, cur, fzt[tid][t]);
            v = fmaf(0.97f, v, cur);
            float s = (v >= 1.25f) ? 1.f : 0.f;
            fst[tid][t] = s;
            fzt[tid][t] = v;
            v *= (1.f - s);
        }
    }
    __syncthreads();
    long base = (long)b * H * T + (long)h0 * T;
    for (int idx = tid; idx < 64 * T; idx += 256) {
        int h = idx / T, t = idx - (idx / T) * T;
        S[base + idx] = fst[h][t];
        V[base + idx] = fzt[h][t];
    }
}

extern "C" void kernel_launch(void* const* d_in, const int* in_sizes, int n_in,
                              void* d_out, int out_size, void* d_ws, size_t ws_size,
                              hipStream_t stream) {
    const float* spike = (const float*)d_in[0];
    const float* w0    = (const float*)d_in[1];
    const float* w1    = (const float*)d_in[2];
    const float* ro0   = (const float*)d_in[3];
    const float* ro1   = (const float*)d_in[4];

    float* out = (float*)d_out;
    float* S = out;
    float* R = out + 2L * B * H * T;
    float* V = out + 2L * B * H * T + 2L * B * O * T;

    const size_t nW0 = (size_t)32 * NKT0 * A_ELEM;
    const size_t nW1 = (size_t)32 * NKT1 * A_ELEM;
    const size_t nX0 = (size_t)B * NKT0 * B_ELEM;
    const size_t nS0 = (size_t)B * NKT1 * B_ELEM;
    const size_t need = (nW0 + nW1 + nX0 + nS0) * sizeof(unsigned short);

    if (ws_size >= need) {
        unsigned short* p = (unsigned short*)d_ws;
        unsigned short* w0img = p; p += nW0;
        unsigned short* w1img = p; p += nW1;
        unsigned short* x0img = p; p += nX0;
        unsigned short* s0img = p; p += nS0;

        hipMemsetAsync(R, 0, 2L * B * O * T * sizeof(float), stream);

        int t0 = 32 * NKT0 * 1024, t1 = 32 * NKT1 * 1024;
        convert_w_tiled<<<(t0 + 255) / 256, 256, 0, stream>>>(w0, I, NKT0, t0, w0img);
        convert_w_tiled<<<(t1 + 255) / 256, 256, 0, stream>>>(w1, H, NKT1, t1, w1img);
        transpose_x_tiled<<<dim3(NKT0, B), 256, 0, stream>>>(spike, x0img);

        gemm_scan_mfma2<<<2048, 256, 0, stream>>>(w0img, x0img, NKT0, ro0, R,
                                                  S, V, s0img);
        gemm_scan_mfma2<<<2048, 256, 0, stream>>>(w1img, s0img, NKT1, ro1,
                                                  R + (size_t)B * O * T,
                                                  S + (size_t)B * H * T,
                                                  V + (size_t)B * H * T, nullptr);
    } else {
        dim3 grid(H / 64, B);
        gemm_scan_f32<<<grid, 256, 0, stream>>>(w0, spike, I, (long)I * T, S, V);
        gemm_scan_f32<<<grid, 256, 0, stream>>>(w1, S, H, (long)H * T,
                                                S + (long)B * H * T, V + (long)B * H * T);
        readout_kernel<<<2 * B * O, 128, 0, stream>>>(ro0, ro1, S, R);
    }
}

// Round 6
// 270.976 us; speedup vs baseline: 12.5674x; 1.2117x over previous
//
#include <hip/hip_runtime.h>

using f16x8 = __attribute__((ext_vector_type(8))) _Float16;
using f32x4 = __attribute__((ext_vector_type(4))) float;
using u16x8 = __attribute__((ext_vector_type(8))) unsigned short;

constexpr int B = 64, I = 700, H = 2048, O = 20, T = 100;
constexpr int NKT0 = 11;        // K-tiles layer 0 (704 = 11*64)
constexpr int NKT1 = 32;        // K-tiles layer 1 (2048 = 32*64)
constexpr int A_ELEM = 8192;    // ushorts per A image: 128 rows (64 hi + 64 lo) x 64
constexpr int B_ELEM = 7168;    // ushorts per B image: 112 rows (t) x 64
constexpr int BUF_BYTES = 30720;
constexpr int A_CHUNKS = 1024, TOT_CHUNKS = 1920;

#define GLOAD16(gp, lp) __builtin_amdgcn_global_load_lds( \
    (const __attribute__((address_space(1))) unsigned int*)(const void*)(gp), \
    (__attribute__((address_space(3))) unsigned int*)(void*)(lp), 16, 0, 0)

// ---------------- pre-pass: W fp32 -> split-f16 A-images, pre-swizzled ----------
__global__ __launch_bounds__(256) void convert_w_tiled(
    const float* __restrict__ w, int K, int NKT, int total,
    unsigned short* __restrict__ dst)
{
    int idx = blockIdx.x * 256 + threadIdx.x;
    if (idx >= total) return;
    int img = idx >> 10, c = idx & 1023;
    int h0blk = img / NKT, kt = img - h0blk * NKT;
    int r = c >> 3, s8 = c & 7;
    int sp = r >> 6, hr = r & 63;
    int kbase = kt * 64 + ((s8 ^ (r & 7)) << 3);
    const float* wrow = w + (size_t)(h0blk * 64 + hr) * K;
    u16x8 outv;
    #pragma unroll
    for (int j = 0; j < 8; ++j) {
        int k = kbase + j;
        float f = (k < K) ? wrow[k] : 0.f;
        _Float16 hi = (_Float16)f;
        _Float16 val = (sp == 0) ? hi : (_Float16)(f - (float)hi);
        outv[j] = *(unsigned short*)&val;
    }
    *(u16x8*)&dst[(size_t)idx * 8] = outv;
}

// ---------------- pre-pass: X fp32 [B][I][T] -> pre-swizzled B-images ----------
__global__ __launch_bounds__(256) void transpose_x_tiled(
    const float* __restrict__ X, unsigned short* __restrict__ XT)
{
    __shared__ float xs[64][101];
    int kt = blockIdx.x, b = blockIdx.y;
    int c0 = kt * 64;
    const float* Xb = X + (size_t)b * I * T;
    for (int idx = threadIdx.x; idx < 64 * T; idx += 256) {
        int ci = idx / T, t = idx - (idx / T) * T;
        xs[ci][t] = (c0 + ci < I) ? Xb[(size_t)(c0 + ci) * T + t] : 0.f;
    }
    __syncthreads();
    unsigned short* dst = XT + ((size_t)b * NKT0 + kt) * B_ELEM;
    for (int idx = threadIdx.x; idx < 896; idx += 256) {
        int r = idx >> 3, s8 = idx & 7;
        int ci0 = (s8 ^ (r & 7)) << 3;
        u16x8 outv;
        #pragma unroll
        for (int j = 0; j < 8; ++j) {
            float f = (r < T) ? xs[ci0 + j][r] : 0.f;
            _Float16 h = (_Float16)f;
            outv[j] = *(unsigned short*)&h;
        }
        *(u16x8*)&dst[(size_t)idx * 8] = outv;
    }
}

// ---------------- pre-pass: ro fp32 [O][H] -> pre-swizzled f16 A-images --------
// dst: [32 h0blk][32 rows (o, zero-pad >=20)][64 cols h], same swizzle as A images.
__global__ __launch_bounds__(256) void convert_ro_tiled(
    const float* __restrict__ ro, unsigned short* __restrict__ dst)
{
    int h0blk = blockIdx.x;           // 0..31
    int c = threadIdx.x;              // chunk 0..255
    int r = c >> 3, s8 = c & 7;
    int hl = (s8 ^ (r & 7)) << 3;
    u16x8 outv;
    #pragma unroll
    for (int j = 0; j < 8; ++j) {
        float f = (r < O) ? ro[(size_t)r * H + h0blk * 64 + hl + j] : 0.f;
        _Float16 hv = (_Float16)f;
        outv[j] = *(unsigned short*)&hv;
    }
    *(u16x8*)&dst[((size_t)h0blk * 256 + c) * 8] = outv;
}

// -- fused MFMA GEMM (2-phase gload_lds pipeline) + CUBA scan + MFMA readout ----
__global__ __launch_bounds__(256, 2) void gemm_scan_mfma2(
    const unsigned short* __restrict__ WA,    // [32][NKT][A_ELEM]
    const unsigned short* __restrict__ XB,    // [64][NKT][B_ELEM]
    int NKT,
    const unsigned short* __restrict__ roimg, // [32][2048] pre-swizzled ro image
    float* __restrict__ Rl,                   // [B][O][T] readout (atomic)
    float* __restrict__ S, float* __restrict__ V,
    unsigned short* __restrict__ sT)          // [64][NKT1][B_ELEM] or null
{
    __shared__ __align__(16) char smem[2 * BUF_BYTES];
    const int tid = threadIdx.x;
    const int lane = tid & 63, wave = tid >> 6;
    const int lm = lane & 15, lg = lane >> 4;
    const int wr = wave >> 1, wc = wave & 1;
    const int NTW = 4 - wc;

    // XCD-aware decode: blocks with same b land on same XCD
    int orig = blockIdx.x;
    int xcd = orig & 7, slot = orig >> 3;
    int b = xcd * 8 + (slot & 7);
    int h0blk = slot >> 3;

    const unsigned short* WAblk = WA + (size_t)h0blk * NKT * A_ELEM;
    const unsigned short* XBb   = XB + (size_t)b * NKT * B_ELEM;

    int offA[2][2][2], offB[4][2];
    #pragma unroll
    for (int sp = 0; sp < 2; ++sp)
        #pragma unroll
        for (int ar = 0; ar < 2; ++ar)
            #pragma unroll
            for (int kh = 0; kh < 2; ++kh) {
                int row = sp * 64 + wr * 32 + ar * 16 + lm;
                int g = kh * 4 + lg;
                offA[sp][ar][kh] = row * 128 + ((g ^ (row & 7)) << 4);
            }
    #pragma unroll
    for (int nt = 0; nt < 4; ++nt)
        #pragma unroll
        for (int kh = 0; kh < 2; ++kh) {
            int row = wc * 64 + nt * 16 + lm;
            int g = kh * 4 + lg;
            offB[nt][kh] = 16384 + row * 128 + ((g ^ (row & 7)) << 4);
        }

    f32x4 acc[2][4];
    #pragma unroll
    for (int ar = 0; ar < 2; ++ar)
        #pragma unroll
        for (int nt = 0; nt < 4; ++nt)
            acc[ar][nt] = (f32x4){0.f, 0.f, 0.f, 0.f};

    // prologue: stage kt=0 into buf 0
    #pragma unroll
    for (int j = 0; j < 8; ++j) {
        int idx = tid + j * 256;
        if (idx < TOT_CHUNKS) {
            char* lb = smem + ((idx & ~63) << 4);
            const unsigned short* g = (idx < A_CHUNKS) ? WAblk + (size_t)idx * 8
                                                       : XBb + (size_t)(idx - A_CHUNKS) * 8;
            GLOAD16(g, lb);
        }
    }
    __syncthreads();

    for (int kt = 0; kt < NKT; ++kt) {
        int cur = kt & 1;
        if (kt + 1 < NKT) {
            const unsigned short* wa = WAblk + (size_t)(kt + 1) * A_ELEM;
            const unsigned short* xb = XBb + (size_t)(kt + 1) * B_ELEM;
            int nb = (cur ^ 1) * BUF_BYTES;
            #pragma unroll
            for (int j = 0; j < 8; ++j) {
                int idx = tid + j * 256;
                if (idx < TOT_CHUNKS) {
                    char* lb = smem + nb + ((idx & ~63) << 4);
                    const unsigned short* g = (idx < A_CHUNKS) ? wa + (size_t)idx * 8
                                                               : xb + (size_t)(idx - A_CHUNKS) * 8;
                    GLOAD16(g, lb);
                }
            }
        }
        const char* base = smem + cur * BUF_BYTES;
        f16x8 afr[2][2][2], bfr[4][2];
        #pragma unroll
        for (int sp = 0; sp < 2; ++sp)
            #pragma unroll
            for (int ar = 0; ar < 2; ++ar)
                #pragma unroll
                for (int kh = 0; kh < 2; ++kh)
                    afr[sp][ar][kh] = *(const f16x8*)(base + offA[sp][ar][kh]);
        #pragma unroll
        for (int nt = 0; nt < 4; ++nt) {
            if (nt >= NTW) continue;
            #pragma unroll
            for (int kh = 0; kh < 2; ++kh)
                bfr[nt][kh] = *(const f16x8*)(base + offB[nt][kh]);
        }
        #pragma unroll
        for (int kh = 0; kh < 2; ++kh)
            #pragma unroll
            for (int ar = 0; ar < 2; ++ar)
                #pragma unroll
                for (int nt = 0; nt < 4; ++nt) {
                    if (nt >= NTW) continue;
                    acc[ar][nt] = __builtin_amdgcn_mfma_f32_16x16x32_f16(
                        afr[0][ar][kh], bfr[nt][kh], acc[ar][nt], 0, 0, 0);
                    acc[ar][nt] = __builtin_amdgcn_mfma_f32_16x16x32_f16(
                        afr[1][ar][kh], bfr[nt][kh], acc[ar][nt], 0, 0, 0);
                }
        __syncthreads();
    }

    // ---- scan phase: reuse LDS ----
    float* zt           = (float*)smem;                       // [64][101] f32 (25856 B)
    unsigned short* img = (unsigned short*)(smem + 25856);    // [112][64] f16 B-image (14336 B)
    unsigned short* roA = (unsigned short*)(smem + 40192);    // [32][64] f16 A-image (4096 B)

    #pragma unroll
    for (int ar = 0; ar < 2; ++ar)
        #pragma unroll
        for (int nt = 0; nt < 4; ++nt) {
            if (nt >= NTW) continue;
            int t = wc * 64 + nt * 16 + lm;
            if (t < T) {
                #pragma unroll
                for (int r = 0; r < 4; ++r) {
                    int h = wr * 32 + ar * 16 + lg * 4 + r;
                    zt[h * 101 + t] = acc[ar][nt][r];
                }
            }
        }
    __syncthreads();

    if (tid < 64) {
        // sequential LIF scan, one chain per h; emit spikes straight into the
        // swizzled f16 B-image (readout B-operand + next layer's tile + S source)
        const int hs = tid >> 3, hj = tid & 7;
        float cur = 0.f, v = 0.f;
        for (int t = 0; t < T; ++t) {
            cur = fmaf(0.75f, cur, zt[tid * 101 + t]);
            v   = fmaf(0.97f, v, cur);
            bool sp = (v >= 1.25f);
            img[t * 64 + ((hs ^ (t & 7)) << 3) + hj] = sp ? 0x3C00 : 0;
            zt[tid * 101 + t] = v;   // pre-reset voltage
            v *= sp ? 0.f : 1.f;
        }
    } else {
        // stage pre-swizzled ro A-image + zero img pad rows 100..111
        const unsigned short* src = roimg + (size_t)h0blk * 2048;
        for (int c = tid - 64; c < 256; c += 192)
            *(u16x8*)&roA[c * 8] = *(const u16x8*)&src[(size_t)c * 8];
        for (int c = tid - 64; c < 96; c += 192)
            *(u16x8*)&img[(800 + c) * 8] = (u16x8){0, 0, 0, 0, 0, 0, 0, 0};
    }
    __syncthreads();

    // ---- fused readout via MFMA: D[o][t] = sum_h roA[o][h] * img[t][h] ----
    {
        int rowR = wr * 16 + lm;
        f16x8 rf[2];
        #pragma unroll
        for (int kh = 0; kh < 2; ++kh) {
            int g = kh * 4 + lg;
            rf[kh] = *(const f16x8*)((const char*)roA + rowR * 128 + ((g ^ (rowR & 7)) << 4));
        }
        #pragma unroll
        for (int nt = 0; nt < 4; ++nt) {
            if (nt >= NTW) continue;
            f32x4 rc = (f32x4){0.f, 0.f, 0.f, 0.f};
            #pragma unroll
            for (int kh = 0; kh < 2; ++kh) {
                int row = wc * 64 + nt * 16 + lm;
                int g = kh * 4 + lg;
                f16x8 bf = *(const f16x8*)((const char*)img + row * 128 + ((g ^ (row & 7)) << 4));
                rc = __builtin_amdgcn_mfma_f32_16x16x32_f16(rf[kh], bf, rc, 0, 0, 0);
            }
            int o = wr * 16 + lg * 4;
            int t = wc * 64 + nt * 16 + lm;
            if (t < T && o < O) {
                #pragma unroll
                for (int r = 0; r < 4; ++r)
                    if (o + r < O)
                        atomicAdd(&Rl[((size_t)b * O + o + r) * T + t], rc[r]);
            }
        }
    }

    // ---- global write-out S, V ----
    size_t gbase = ((size_t)b * H + h0blk * 64) * T;
    for (int idx = tid; idx < 1600; idx += 256) {
        int h = idx / 25, q = idx - (idx / 25) * 25;
        int t0 = q * 4;
        int hs = h >> 3, hj = h & 7;
        f32x4 sv, vv;
        #pragma unroll
        for (int i = 0; i < 4; ++i) {
            int t = t0 + i;
            sv[i] = img[t * 64 + ((hs ^ (t & 7)) << 3) + hj] ? 1.f : 0.f;
            vv[i] = zt[h * 101 + t];
        }
        *(f32x4*)&S[gbase + (size_t)h * 100 + t0] = sv;
        *(f32x4*)&V[gbase + (size_t)h * 100 + t0] = vv;
    }
    if (sT) {  // img already IS the next layer's pre-swizzled B-image tile
        unsigned short* dst = sT + ((size_t)b * NKT1 + h0blk) * B_ELEM;
        for (int idx = tid; idx < 896; idx += 256)
            *(u16x8*)&dst[(size_t)idx * 8] = *(const u16x8*)&img[(size_t)idx * 8];
    }
}

// ---------------- standalone readout (fallback path only) ----------------
__global__ __launch_bounds__(128) void readout_kernel(
    const float* __restrict__ ro0, const float* __restrict__ ro1,
    const float* __restrict__ Sall, float* __restrict__ R)
{
    int bid = blockIdx.x;
    int l = bid / (B * O);
    int rem = bid - l * (B * O);
    int b = rem / O, o = rem - (rem / O) * O;
    int t = threadIdx.x;
    if (t >= T) return;
    const float* ro = (l == 0 ? ro0 : ro1) + (size_t)o * H;
    const float* s  = Sall + (size_t)l * B * H * T + (size_t)b * H * T + t;
    float acc = 0.f;
    #pragma unroll 8
    for (int h = 0; h < H; ++h)
        acc = fmaf(ro[h], s[(size_t)h * T], acc);
    R[(size_t)l * B * O * T + (size_t)b * O * T + (size_t)o * T + t] = acc;
}

// ---------------- fallback fp32 path (round-1, known correct) ----------------
__global__ __launch_bounds__(256) void gemm_scan_f32(
    const float* __restrict__ W, const float* __restrict__ X,
    int K, long xbs, float* __restrict__ S, float* __restrict__ V)
{
    __shared__ float fxs[16][112];
    __shared__ float fwl[64][16];
    __shared__ float fzt[64][101];
    __shared__ float fst[64][101];
    const int tid = threadIdx.x;
    const int tx = tid & 15, ty = tid >> 4;
    const int b = blockIdx.y, h0 = blockIdx.x * 64;
    const float* Xb = X + (long)b * xbs;
    float acc[4][7];
    #pragma unroll
    for (int k = 0; k < 4; ++k)
        #pragma unroll
        for (int j = 0; j < 7; ++j) acc[k][j] = 0.f;
    for (int cc = 0; cc < K; cc += 16) {
        for (int idx = tid; idx < 16 * 112; idx += 256) {
            int c = idx / 112, t = idx - c * 112;
            float v = 0.f;
            if (t < T && cc + c < K) v = Xb[(long)(cc + c) * T + t];
            fxs[c][t] = v;
        }
        for (int idx = tid; idx < 64 * 16; idx += 256) {
            int h = idx >> 4, c = idx & 15;
            float v = 0.f;
            if (cc + c < K) v = W[(long)(h0 + h) * K + cc + c];
            fwl[h][c] = v;
        }
        __syncthreads();
        #pragma unroll
        for (int c = 0; c < 16; ++c) {
            float wv[4], xv[7];
            #pragma unroll
            for (int k = 0; k < 4; ++k) wv[k] = fwl[ty + 16 * k][c];
            #pragma unroll
            for (int j = 0; j < 7; ++j) xv[j] = fxs[c][tx + 16 * j];
            #pragma unroll
            for (int k = 0; k < 4; ++k)
                #pragma unroll
                for (int j = 0; j < 7; ++j)
                    acc[k][j] = fmaf(wv[k], xv[j], acc[k][j]);
        }
        __syncthreads();
    }
    #pragma unroll
    for (int k = 0; k < 4; ++k)
        #pragma unroll
        for (int j = 0; j < 7; ++j) {
            int t = tx + 16 * j;
            if (t < T) fzt[ty + 16 * k][t] = acc[k][j];
        }
    __syncthreads();
    if (tid < 64) {
        float cur = 0.f, v = 0.f;
        for (int t = 0; t < T; ++t) {
            cur = fmaf(0.75f, cur, fzt[tid][t]);
            v = fmaf(0.97f, v, cur);
            float s = (v >= 1.25f) ? 1.f : 0.f;
            fst[tid][t] = s;
            fzt[tid][t] = v;
            v *= (1.f - s);
        }
    }
    __syncthreads();
    long base = (long)b * H * T + (long)h0 * T;
    for (int idx = tid; idx < 64 * T; idx += 256) {
        int h = idx / T, t = idx - (idx / T) * T;
        S[base + idx] = fst[h][t];
        V[base + idx] = fzt[h][t];
    }
}

extern "C" void kernel_launch(void* const* d_in, const int* in_sizes, int n_in,
                              void* d_out, int out_size, void* d_ws, size_t ws_size,
                              hipStream_t stream) {
    const float* spike = (const float*)d_in[0];
    const float* w0    = (const float*)d_in[1];
    const float* w1    = (const float*)d_in[2];
    const float* ro0   = (const float*)d_in[3];
    const float* ro1   = (const float*)d_in[4];

    float* out = (float*)d_out;
    float* S = out;
    float* R = out + 2L * B * H * T;
    float* V = out + 2L * B * H * T + 2L * B * O * T;

    const size_t nW0 = (size_t)32 * NKT0 * A_ELEM;
    const size_t nW1 = (size_t)32 * NKT1 * A_ELEM;
    const size_t nX0 = (size_t)B * NKT0 * B_ELEM;
    const size_t nS0 = (size_t)B * NKT1 * B_ELEM;
    const size_t nRO = (size_t)32 * 2048;           // per-layer ro image
    const size_t need = (nW0 + nW1 + nX0 + nS0 + 2 * nRO) * sizeof(unsigned short);

    if (ws_size >= need) {
        unsigned short* p = (unsigned short*)d_ws;
        unsigned short* w0img = p; p += nW0;
        unsigned short* w1img = p; p += nW1;
        unsigned short* x0img = p; p += nX0;
        unsigned short* s0img = p; p += nS0;
        unsigned short* r0img = p; p += nRO;
        unsigned short* r1img = p; p += nRO;

        hipMemsetAsync(R, 0, 2L * B * O * T * sizeof(float), stream);

        int t0 = 32 * NKT0 * 1024, t1 = 32 * NKT1 * 1024;
        convert_w_tiled<<<(t0 + 255) / 256, 256, 0, stream>>>(w0, I, NKT0, t0, w0img);
        convert_w_tiled<<<(t1 + 255) / 256, 256, 0, stream>>>(w1, H, NKT1, t1, w1img);
        transpose_x_tiled<<<dim3(NKT0, B), 256, 0, stream>>>(spike, x0img);
        convert_ro_tiled<<<32, 256, 0, stream>>>(ro0, r0img);
        convert_ro_tiled<<<32, 256, 0, stream>>>(ro1, r1img);

        gemm_scan_mfma2<<<2048, 256, 0, stream>>>(w0img, x0img, NKT0, r0img, R,
                                                  S, V, s0img);
        gemm_scan_mfma2<<<2048, 256, 0, stream>>>(w1img, s0img, NKT1, r1img,
                                                  R + (size_t)B * O * T,
                                                  S + (size_t)B * H * T,
                                                  V + (size_t)B * H * T, nullptr);
    } else {
        dim3 grid(H / 64, B);
        gemm_scan_f32<<<grid, 256, 0, stream>>>(w0, spike, I, (long)I * T, S, V);
        gemm_scan_f32<<<grid, 256, 0, stream>>>(w1, S, H, (long)H * T,
                                                S + (long)B * H * T, V + (long)B * H * T);
        readout_kernel<<<2 * B * O, 128, 0, stream>>>(ro0, ro1, S, R);
    }
}